// Round 6
// baseline (59.305 us; speedup 1.0000x reference)
//
#include <hip/hip_runtime.h>

// Problem constants: N=8, C=1024, D=128, K=64, R=256
#define N_ 8
#define C_ 1024
#define D_ 128
#define K_ 64
#define R_ 256
#define TC 16          // c-rows per block
#define XPAD 132       // padded LDS row stride (132%32=4 -> spreads banks)

typedef float fvec4 __attribute__((ext_vector_type(4)));

// out[n,c,k,d] = (xhat[n,c,d] - cent[n,k,d]) / (8 * ||xhat[n,c]-cent[n,k]||)
// (softmax cancels under the per-k l2norm; final l2norm over K*D == sqrt(K)=8)
//
// R5 restructure: block = (n, 16-row c-tile); distances are THREAD-LOCAL dots
// (no 5-deep butterfly chains -> DS pipe freed); store phase is a pure burst:
// 8 cent float4s live in registers, x̂ from LDS broadcast, 128 stores/thread.
__global__ __launch_bounds__(256) void vlad_tiled_kernel(
    const float* __restrict__ x,            // (N, C, D)
    const float* __restrict__ cluster,      // (N, R, D)
    const int*   __restrict__ cluster_idx,  // (K,)
    float*       __restrict__ out)          // (N, C, K*D)
{
    __shared__ float xh[TC][XPAD];   // normalized x rows
    __shared__ float id_s[TC][K_];   // 0.125 / dist(c,k)
    __shared__ float part1[TC][16];  // norm partials
    __shared__ float rinv_s[TC];
    __shared__ int   coff[K_];       // cluster_idx[k] * D

    const int bid = blockIdx.x;
    const int n   = bid & 7;               // one n per XCD-ish; keeps cent L1-hot
    const int c0  = (bid >> 3) * TC;
    const int t   = threadIdx.x;

    if (t < K_) coff[t] = cluster_idx[t] * D_;

    // ---- Phase 1: load 16 x rows, row norms, write normalized rows to LDS ----
    const int r = t >> 4, s = t & 15;      // row, 8-float segment
    const float* xrow = x + (size_t)(n * C_ + c0 + r) * D_ + s * 8;
    fvec4 xa = *(const fvec4*)xrow;
    fvec4 xb = *(const fvec4*)(xrow + 4);
    part1[r][s] = xa.x*xa.x + xa.y*xa.y + xa.z*xa.z + xa.w*xa.w
                + xb.x*xb.x + xb.y*xb.y + xb.z*xb.z + xb.w*xb.w;
    __syncthreads();
    if (t < TC) {
        const fvec4* pp = (const fvec4*)part1[t];
        fvec4 v = pp[0] + pp[1] + pp[2] + pp[3];
        rinv_s[t] = 1.0f / fmaxf(sqrtf(v.x + v.y + v.z + v.w), 1e-12f);
    }
    __syncthreads();
    const float rv = rinv_s[r];
    xa *= rv; xb *= rv;
    *(fvec4*)&xh[r][s * 8]     = xa;
    *(fvec4*)&xh[r][s * 8 + 4] = xb;
    __syncthreads();

    // ---- Phase 2: distances, thread-local. thread = (c=t&15, g=(t>>4)&3, kb=t>>6)
    // Each thread: d-slice [32g,32g+32) partial for 16 k's; combine the 4 g
    // partials with two shfl_xor (lanes l, l^16, l^32 share c within a wave).
    {
        const int c  = t & 15;
        const int g  = (t >> 4) & 3;
        const int kb = t >> 6;             // == wave id, uniform per wave
        const float* cb = cluster + (size_t)n * (R_ * D_) + g * 32;
        fvec4 xr[8];
        #pragma unroll
        for (int j = 0; j < 8; ++j) xr[j] = *(const fvec4*)&xh[c][g * 32 + j * 4];
        for (int ki = 0; ki < 16; ++ki) {
            const int k = kb * 16 + ki;
            const float* crow = cb + coff[k];
            float acc = 0.f;
            #pragma unroll
            for (int j = 0; j < 8; ++j) {
                fvec4 cv = *(const fvec4*)(crow + j * 4);
                fvec4 d  = xr[j] - cv;
                acc = fmaf(d.x, d.x, fmaf(d.y, d.y, fmaf(d.z, d.z, fmaf(d.w, d.w, acc))));
            }
            acc += __shfl_xor(acc, 16);
            acc += __shfl_xor(acc, 32);
            if (g == 0) id_s[c][k] = 0.125f / fmaxf(sqrtf(acc), 1e-12f);
        }
    }
    __syncthreads();

    // ---- Phase 3: pure store burst. thread = (d4=t&31, h=t>>5); k in {8q+h}.
    // The 8 cent float4s this thread ever needs sit in registers; x̂ row from
    // LDS (all lanes same row, 2-way broadcast = free); 128 coalesced stores.
    const int d4 = t & 31, h = t >> 5;
    const float* cb2 = cluster + (size_t)n * (R_ * D_) + d4 * 4;
    fvec4 cv[8];
    #pragma unroll
    for (int q = 0; q < 8; ++q) cv[q] = *(const fvec4*)(cb2 + coff[q * 8 + h]);
    float* ob = out + (size_t)(n * C_ + c0) * (K_ * D_) + h * D_ + d4 * 4;
    for (int cc = 0; cc < TC; ++cc) {
        const fvec4 xv = *(const fvec4*)&xh[cc][d4 * 4];
        float* oc = ob + (size_t)cc * (K_ * D_);
        #pragma unroll
        for (int q = 0; q < 8; ++q) {
            const float idv = id_s[cc][q * 8 + h];
            *(fvec4*)(oc + q * 8 * D_) = (xv - cv[q]) * idv;
        }
    }
}

extern "C" void kernel_launch(void* const* d_in, const int* in_sizes, int n_in,
                              void* d_out, int out_size, void* d_ws, size_t ws_size,
                              hipStream_t stream) {
    const float* x           = (const float*)d_in[0];
    const float* cluster     = (const float*)d_in[1];
    // d_in[2] = conv_w, d_in[3] = conv_b: mathematically cancelled, unused.
    const int*   cluster_idx = (const int*)d_in[4];
    float* out = (float*)d_out;

    dim3 grid(N_ * C_ / TC), block(256);   // 512 blocks = 8 n x 64 c-tiles
    vlad_tiled_kernel<<<grid, block, 0, stream>>>(x, cluster, cluster_idx, out);
}